// Round 4
// baseline (438.870 us; speedup 1.0000x reference)
//
#include <hip/hip_runtime.h>
#include <hip/hip_bf16.h>
#include <math.h>

#define B_TOK 16384
#define DDIM  1024
#define NEXP  6
#define NPAIR 15
#define HDIM  256
#define EPSF  0.1f
#define TILE  32
#define MAXTILES (B_TOK / TILE + NPAIR)   // 527

typedef float f32x4 __attribute__((ext_vector_type(4)));
typedef short bf16x8 __attribute__((ext_vector_type(8)));

__device__ __forceinline__ unsigned short f2bf(float f) {
    unsigned int u = __float_as_uint(f);
    u += 0x7FFFu + ((u >> 16) & 1u);
    return (unsigned short)(u >> 16);
}
__device__ __forceinline__ int pack2bf(float a, float b) {
    return (int)f2bf(a) | ((int)f2bf(b) << 16);
}
__device__ __forceinline__ float gelu_exact(float v) {
    return 0.5f * v * (1.0f + erff(v * 0.70710678118654752440f));
}

// ---------- transpose + convert: per-slice src (R x C) f32 -> dst (C x R) bf16
__global__ __launch_bounds__(256) void transpose_convert_kernel(
    const float* __restrict__ src, unsigned short* __restrict__ dst, int R, int C) {
    __shared__ float tile[32][33];
    const int e = blockIdx.z;
    const float* s = src + (size_t)e * R * C;
    unsigned short* d = dst + (size_t)e * R * C;
    const int cb = blockIdx.x * 32;
    const int rb = blockIdx.y * 32;
    const int tx = threadIdx.x;
    const int ty = threadIdx.y;
#pragma unroll
    for (int i = 0; i < 4; ++i)
        tile[ty + i * 8][tx] = s[(size_t)(rb + ty + i * 8) * C + cb + tx];
    __syncthreads();
#pragma unroll
    for (int i = 0; i < 4; ++i)
        d[(size_t)(cb + ty + i * 8) * R + rb + tx] = f2bf(tile[tx][ty + i * 8]);
}

// ---------- router phase 1: logits, softmax, eps-mix, top-2 -> per-token records
__global__ __launch_bounds__(256) void router1_kernel(
    const float* __restrict__ x, const float* __restrict__ Wr, const float* __restrict__ br,
    int* __restrict__ erec, float2* __restrict__ wrec, float* __restrict__ partial) {
    __shared__ float ls[NEXP];
    const int tid = threadIdx.x;
    if (tid < NEXP) ls[tid] = 0.0f;
    __syncthreads();

    const int wave = tid >> 6;
    const int lane = tid & 63;
    const int tok0 = blockIdx.x * 16 + wave * 4;

    float acc[4][NEXP];
#pragma unroll
    for (int j = 0; j < 4; ++j)
#pragma unroll
        for (int e = 0; e < NEXP; ++e) acc[j][e] = 0.0f;

#pragma unroll
    for (int it = 0; it < 4; ++it) {
        const float4* w4 = reinterpret_cast<const float4*>(
            Wr + (size_t)(it * 256 + lane * 4) * NEXP);
        float w[24];
#pragma unroll
        for (int q = 0; q < 6; ++q) *reinterpret_cast<float4*>(&w[q * 4]) = w4[q];
#pragma unroll
        for (int j = 0; j < 4; ++j) {
            float4 xv = reinterpret_cast<const float4*>(
                x + (size_t)(tok0 + j) * DDIM)[it * 64 + lane];
            float xa[4] = {xv.x, xv.y, xv.z, xv.w};
#pragma unroll
            for (int i2 = 0; i2 < 4; ++i2)
#pragma unroll
                for (int e = 0; e < NEXP; ++e)
                    acc[j][e] += xa[i2] * w[i2 * NEXP + e];
        }
    }

    float lsacc[NEXP];
#pragma unroll
    for (int e = 0; e < NEXP; ++e) lsacc[e] = 0.0f;

#pragma unroll
    for (int j = 0; j < 4; ++j) {
        float p[NEXP];
        float m = -1e30f;
#pragma unroll
        for (int e = 0; e < NEXP; ++e) {
            float v = acc[j][e];
#pragma unroll
            for (int off = 32; off > 0; off >>= 1) v += __shfl_xor(v, off, 64);
            p[e] = v + br[e];
            m = fmaxf(m, p[e]);
        }
        float s = 0.0f;
#pragma unroll
        for (int e = 0; e < NEXP; ++e) { p[e] = expf(p[e] - m); s += p[e]; }
        const float inv = (1.0f - EPSF) / s;
#pragma unroll
        for (int e = 0; e < NEXP; ++e) p[e] = p[e] * inv + EPSF / (float)NEXP;

        int b1i = 0; float bp = p[0];
#pragma unroll
        for (int e = 1; e < NEXP; ++e) if (p[e] > bp) { bp = p[e]; b1i = e; }
        int b2i = -1; float sp = -1e30f;
#pragma unroll
        for (int e = 0; e < NEXP; ++e) if (e != b1i && p[e] > sp) { sp = p[e]; b2i = e; }

        if (lane == 0) {
            erec[tok0 + j] = b1i | (b2i << 16);
            wrec[tok0 + j] = make_float2(bp, sp);
        }
#pragma unroll
        for (int e = 0; e < NEXP; ++e) lsacc[e] += p[e];
    }

    if (lane == 0) {
#pragma unroll
        for (int e = 0; e < NEXP; ++e) atomicAdd(&ls[e], lsacc[e]);
    }
    __syncthreads();
    if (tid < NEXP) partial[blockIdx.x * NEXP + tid] = ls[tid];
}

// ---------- router phase 2: bucket tokens by unordered expert pair
__global__ __launch_bounds__(1024) void router2_kernel(
    const int* __restrict__ erec, const float2* __restrict__ wrec,
    int* __restrict__ plist, float2* __restrict__ wpair, int* __restrict__ cnt) {
    __shared__ int lc[NPAIR];
    __shared__ int gb[NPAIR];
    const int tid = threadIdx.x;
    if (tid < NPAIR) lc[tid] = 0;
    __syncthreads();

    const int tok = blockIdx.x * 1024 + tid;
    const int er = erec[tok];
    const float2 wr = wrec[tok];
    const int e1 = er & 0xffff;
    const int e2 = er >> 16;
    const int a = min(e1, e2);
    const int b = max(e1, e2);
    const float wa = (a == e1) ? wr.x : wr.y;
    const float wb = (a == e1) ? wr.y : wr.x;
    const int p = a * (11 - a) / 2 + (b - a - 1);

    const int i = atomicAdd(&lc[p], 1);
    __syncthreads();
    if (tid < NPAIR) gb[tid] = atomicAdd(&cnt[tid], lc[tid]);
    __syncthreads();

    const int pos = gb[p] + i;
    plist[p * B_TOK + pos] = tok;
    wpair[p * B_TOK + pos] = make_float2(wa, wb);
}

// ---------- router phase 3 + aux: tile table, and aux scalar (fused, one block)
__global__ void router3_aux_kernel(const int* __restrict__ cnt, int* __restrict__ table,
                                   const float* __restrict__ partial, float* __restrict__ out) {
    const int lane = threadIdx.x;   // 64
    if (lane == 0) {
        int off = 0;
        for (int p = 0; p < NPAIR; ++p) {
            const int t = (cnt[p] + TILE - 1) / TILE;
            for (int i = 0; i < t; ++i) table[1 + off + i] = (p << 16) | i;
            off += t;
        }
        table[0] = off;
    }
    float s[NEXP];
#pragma unroll
    for (int e = 0; e < NEXP; ++e) s[e] = 0.0f;
    for (int i = lane; i < 1024; i += 64) {
#pragma unroll
        for (int e = 0; e < NEXP; ++e) s[e] += partial[i * NEXP + e];
    }
#pragma unroll
    for (int e = 0; e < NEXP; ++e) {
        float v = s[e];
#pragma unroll
        for (int off = 32; off > 0; off >>= 1) v += __shfl_xor(v, off, 64);
        s[e] = v;
    }
    if (lane == 0) {
        float a = 0.0f;
#pragma unroll
        for (int e = 0; e < NEXP; ++e) {
            float ld = s[e] / (float)B_TOK;
            a += ld * logf(ld * (float)NEXP + 1e-9f);
        }
        out[(size_t)B_TOK * DDIM] = a / logf((float)NEXP + 1e-9f);
    }
}

// ---------- pair-fused expert MLP: 32-token tile, 8 waves, whole-x-in-LDS, barrier-free K-loop
__global__ __launch_bounds__(512, 4) void expert_kernel(
    const float* __restrict__ x,
    const unsigned short* __restrict__ w1t,   // (E, H, D) bf16
    const unsigned short* __restrict__ w2t,   // (E, D, H) bf16
    const float* __restrict__ b1,             // (E, H)
    const float* __restrict__ b2,             // (E, D)
    const int* __restrict__ plist, const float2* __restrict__ wpair,
    const int* __restrict__ cnt, const int* __restrict__ table,
    float* __restrict__ out) {
    const int g = blockIdx.x;
    if (g >= table[0]) return;
    const int code = table[1 + g];
    const int p = code >> 16;
    const int lt = code & 0xffff;
    const int n = cnt[p];

    int a, b;
    if      (p < 5)  { a = 0; b = p + 1; }
    else if (p < 9)  { a = 1; b = p - 3; }
    else if (p < 12) { a = 2; b = p - 6; }
    else if (p < 14) { a = 3; b = p - 8; }
    else             { a = 4; b = 5; }

    __shared__ int   tok_l[TILE];
    __shared__ float wa_l[TILE];
    __shared__ float wb_l[TILE];
    // x tile: 32 tok x 1024 k bf16 = 64KB, token-major rows of 2KB, 16B-chunk XOR swizzle.
    // hA [0,16KB) / hB [16KB,32KB) alias the x region after stage-1 completes.
    __shared__ __align__(16) char smem[65536];

    const int tid = threadIdx.x;
    const int lane = tid & 63;
    const int wave = tid >> 6;

    if (tid < TILE) {
        const int gi = lt * TILE + tid;
        if (gi < n) {
            tok_l[tid] = plist[p * B_TOK + gi];
            float2 w2v = wpair[p * B_TOK + gi];
            wa_l[tid] = w2v.x; wb_l[tid] = w2v.y;
        } else { tok_l[tid] = -1; wa_l[tid] = 0.0f; wb_l[tid] = 0.0f; }
    }
    __syncthreads();

    // ---- stage whole x tile into LDS (bf16, swizzled); 16 threads per token
    {
        const int ti = tid >> 4;          // token slot 0..31
        const int q  = tid & 15;
        const int tok_s = tok_l[ti];
        const float* xrow = x + (size_t)(tok_s < 0 ? 0 : tok_s) * DDIM;
#pragma unroll
        for (int it = 0; it < 8; ++it) {
            const int k0 = it * 128 + q * 8;
            float4 f0, f1;
            if (tok_s >= 0) {
                const float4* ps = reinterpret_cast<const float4*>(xrow + k0);
                f0 = ps[0]; f1 = ps[1];
            } else {
                f0 = make_float4(0.f, 0.f, 0.f, 0.f); f1 = f0;
            }
            int4 wv;
            wv.x = pack2bf(f0.x, f0.y); wv.y = pack2bf(f0.z, f0.w);
            wv.z = pack2bf(f1.x, f1.y); wv.w = pack2bf(f1.z, f1.w);
            const int c = k0 >> 3;        // 16B chunk index 0..127
            *reinterpret_cast<int4*>(smem + ti * 2048 + ((c ^ (ti & 7)) << 4)) = wv;
        }
    }
    __syncthreads();

    // ---- stage 1: hX^T(256 x 32) = wX * gelu(W1X^T . x^T + b1X)
    // waves 0-3 -> expert a, waves 4-7 -> expert b; each wave owns 64 h rows.
    const int wexp = (wave < 4) ? a : b;
    const unsigned short* w1e = w1t + (size_t)wexp * HDIM * DDIM;
    const int hrow0 = (wave & 3) * 64;
    const int kofs = (lane >> 4) * 8;

    f32x4 zero4 = {0.f, 0.f, 0.f, 0.f};
    f32x4 acc[4][2];
#pragma unroll
    for (int i = 0; i < 4; ++i) { acc[i][0] = zero4; acc[i][1] = zero4; }

#pragma unroll 4
    for (int kk = 0; kk < DDIM; kk += 32) {
        bf16x8 aF[4], bF[2];
#pragma unroll
        for (int nt = 0; nt < 2; ++nt) {
            const int t = nt * 16 + (lane & 15);
            const int c = (kk >> 3) + (lane >> 4);
            bF[nt] = *reinterpret_cast<const bf16x8*>(
                smem + t * 2048 + ((c ^ (t & 7)) << 4));
        }
#pragma unroll
        for (int mt = 0; mt < 4; ++mt)
            aF[mt] = *reinterpret_cast<const bf16x8*>(
                w1e + (size_t)(hrow0 + mt * 16 + (lane & 15)) * DDIM + kk + kofs);
#pragma unroll
        for (int mt = 0; mt < 4; ++mt)
#pragma unroll
            for (int nt = 0; nt < 2; ++nt)
                acc[mt][nt] = __builtin_amdgcn_mfma_f32_16x16x32_bf16(
                    aF[mt], bF[nt], acc[mt][nt], 0, 0, 0);
    }
    __syncthreads();   // all x reads done; x region may be overwritten

    // gelu + gate-weight scale + write h^T (bf16): hA at 0, hB at 16KB
    char* hdst = smem + ((wave < 4) ? 0 : 16384);
#pragma unroll
    for (int mt = 0; mt < 4; ++mt) {
        const int hh0 = hrow0 + mt * 16 + (lane >> 4) * 4;
        const float4 bb = *reinterpret_cast<const float4*>(b1 + wexp * HDIM + hh0);
#pragma unroll
        for (int nt = 0; nt < 2; ++nt) {
            const int t = nt * 16 + (lane & 15);
            const float wt = (wave < 4) ? wa_l[t] : wb_l[t];
            ushort4 hv;
            hv.x = f2bf(wt * gelu_exact(acc[mt][nt][0] + bb.x));
            hv.y = f2bf(wt * gelu_exact(acc[mt][nt][1] + bb.y));
            hv.z = f2bf(wt * gelu_exact(acc[mt][nt][2] + bb.z));
            hv.w = f2bf(wt * gelu_exact(acc[mt][nt][3] + bb.w));
            int off = t * 512 + hh0 * 2; off ^= (t & 7) << 4;
            *reinterpret_cast<ushort4*>(hdst + off) = hv;
        }
    }
    __syncthreads();

    // ---- stage 2: out(32 x 1024) = hA . W2A + hB . W2B + (wa*b2A + wb*b2B)
    // 8 waves x 128 d-columns each.
    const unsigned short* w2a = w2t + (size_t)a * DDIM * HDIM;
    const unsigned short* w2b = w2t + (size_t)b * DDIM * HDIM;
#pragma unroll 1
    for (int c2 = 0; c2 < 2; ++c2) {
        const int dbase = wave * 128 + c2 * 64;
        f32x4 a2[2][4];
#pragma unroll
        for (int i = 0; i < 2; ++i)
#pragma unroll
            for (int j = 0; j < 4; ++j) a2[i][j] = zero4;

#pragma unroll
        for (int hh0 = 0; hh0 < HDIM; hh0 += 32) {
            bf16x8 aF[2], bF[4];
#pragma unroll
            for (int mt = 0; mt < 2; ++mt) {
                const int t = mt * 16 + (lane & 15);
                int off = t * 512 + (hh0 + kofs) * 2; off ^= (t & 7) << 4;
                aF[mt] = *reinterpret_cast<const bf16x8*>(smem + off);
            }
#pragma unroll
            for (int nt = 0; nt < 4; ++nt)
                bF[nt] = *reinterpret_cast<const bf16x8*>(
                    w2a + (size_t)(dbase + nt * 16 + (lane & 15)) * HDIM + hh0 + kofs);
#pragma unroll
            for (int mt = 0; mt < 2; ++mt)
#pragma unroll
                for (int nt = 0; nt < 4; ++nt)
                    a2[mt][nt] = __builtin_amdgcn_mfma_f32_16x16x32_bf16(
                        aF[mt], bF[nt], a2[mt][nt], 0, 0, 0);
        }
#pragma unroll
        for (int hh0 = 0; hh0 < HDIM; hh0 += 32) {
            bf16x8 aF[2], bF[4];
#pragma unroll
            for (int mt = 0; mt < 2; ++mt) {
                const int t = mt * 16 + (lane & 15);
                int off = t * 512 + (hh0 + kofs) * 2; off ^= (t & 7) << 4;
                aF[mt] = *reinterpret_cast<const bf16x8*>(smem + 16384 + off);
            }
#pragma unroll
            for (int nt = 0; nt < 4; ++nt)
                bF[nt] = *reinterpret_cast<const bf16x8*>(
                    w2b + (size_t)(dbase + nt * 16 + (lane & 15)) * HDIM + hh0 + kofs);
#pragma unroll
            for (int mt = 0; mt < 2; ++mt)
#pragma unroll
                for (int nt = 0; nt < 4; ++nt)
                    a2[mt][nt] = __builtin_amdgcn_mfma_f32_16x16x32_bf16(
                        aF[mt], bF[nt], a2[mt][nt], 0, 0, 0);
        }

        // epilogue: single plain store per output element
#pragma unroll
        for (int mt = 0; mt < 2; ++mt) {
            const int t0 = mt * 16 + (lane >> 4) * 4;
            int tkj[4]; float waj[4], wbj[4];
#pragma unroll
            for (int j = 0; j < 4; ++j) {
                tkj[j] = tok_l[t0 + j]; waj[j] = wa_l[t0 + j]; wbj[j] = wb_l[t0 + j];
            }
#pragma unroll
            for (int nt = 0; nt < 4; ++nt) {
                const int d = dbase + nt * 16 + (lane & 15);
                const float bA = b2[a * DDIM + d];
                const float bB = b2[b * DDIM + d];
#pragma unroll
                for (int j = 0; j < 4; ++j) {
                    if (tkj[j] >= 0)
                        out[(size_t)tkj[j] * DDIM + d] =
                            a2[mt][nt][j] + waj[j] * bA + wbj[j] * bB;
                }
            }
        }
    }
}

extern "C" void kernel_launch(void* const* d_in, const int* in_sizes, int n_in,
                              void* d_out, int out_size, void* d_ws, size_t ws_size,
                              hipStream_t stream) {
    const float* x  = (const float*)d_in[0];
    const float* Wr = (const float*)d_in[1];
    const float* br = (const float*)d_in[2];
    const float* W1 = (const float*)d_in[3];
    const float* b1 = (const float*)d_in[4];
    const float* W2 = (const float*)d_in[5];
    const float* b2 = (const float*)d_in[6];
    float* out = (float*)d_out;

    char* ws = (char*)d_ws;
    unsigned short* w1t   = (unsigned short*)(ws + 0);          // 3,145,728
    unsigned short* w2t   = (unsigned short*)(ws + 3145728);    // 3,145,728
    int*            plist = (int*)(ws + 6291456);               //   983,040
    float2*         wpair = (float2*)(ws + 7274496);            // 1,966,080
    int*            erec  = (int*)(ws + 9240576);               //    65,536
    float2*         wrec  = (float2*)(ws + 9306112);            //   131,072
    float*          partial = (float*)(ws + 9437184);           //    24,576
    int*            cnt   = (int*)(ws + 9461760);               //       256
    int*            table = (int*)(ws + 9462016);               //     2,560

    hipMemsetAsync(cnt, 0, 256, stream);

    transpose_convert_kernel<<<dim3(HDIM / 32, DDIM / 32, NEXP), dim3(32, 8), 0, stream>>>(
        W1, w1t, DDIM, HDIM);
    transpose_convert_kernel<<<dim3(DDIM / 32, HDIM / 32, NEXP), dim3(32, 8), 0, stream>>>(
        W2, w2t, HDIM, DDIM);

    router1_kernel<<<dim3(B_TOK / 16), dim3(256), 0, stream>>>(x, Wr, br, erec, wrec, partial);
    router2_kernel<<<dim3(B_TOK / 1024), dim3(1024), 0, stream>>>(erec, wrec, plist, wpair, cnt);
    router3_aux_kernel<<<1, 64, 0, stream>>>(cnt, table, partial, out);
    expert_kernel<<<dim3(MAXTILES), dim3(512), 0, stream>>>(
        x, w1t, w2t, b1, b2, plist, wpair, cnt, table, out);
}

// Round 7
// 386.749 us; speedup vs baseline: 1.1348x; 1.1348x over previous
//
#include <hip/hip_runtime.h>
#include <hip/hip_bf16.h>
#include <math.h>

#define B_TOK 16384
#define DDIM  1024
#define NEXP  6
#define NPAIR 15
#define HDIM  256
#define EPSF  0.1f
#define TILE  32
#define MAXTILES (B_TOK / TILE + NPAIR)   // 527

typedef float f32x4 __attribute__((ext_vector_type(4)));
typedef short bf16x8 __attribute__((ext_vector_type(8)));

__device__ __forceinline__ unsigned short f2bf(float f) {
    unsigned int u = __float_as_uint(f);
    u += 0x7FFFu + ((u >> 16) & 1u);
    return (unsigned short)(u >> 16);
}
__device__ __forceinline__ int pack2bf(float a, float b) {
    return (int)f2bf(a) | ((int)f2bf(b) << 16);
}
__device__ __forceinline__ float gelu_exact(float v) {
    return 0.5f * v * (1.0f + erff(v * 0.70710678118654752440f));
}

// ---------- transpose + convert: per-slice src (R x C) f32 -> dst (C x R) bf16
__global__ __launch_bounds__(256) void transpose_convert_kernel(
    const float* __restrict__ src, unsigned short* __restrict__ dst, int R, int C) {
    __shared__ float tile[32][33];
    const int e = blockIdx.z;
    const float* s = src + (size_t)e * R * C;
    unsigned short* d = dst + (size_t)e * R * C;
    const int cb = blockIdx.x * 32;
    const int rb = blockIdx.y * 32;
    const int tx = threadIdx.x;
    const int ty = threadIdx.y;
#pragma unroll
    for (int i = 0; i < 4; ++i)
        tile[ty + i * 8][tx] = s[(size_t)(rb + ty + i * 8) * C + cb + tx];
    __syncthreads();
#pragma unroll
    for (int i = 0; i < 4; ++i)
        d[(size_t)(cb + ty + i * 8) * R + rb + tx] = f2bf(tile[tx][ty + i * 8]);
}

// ---------- router phase 1: logits, softmax, eps-mix, top-2 -> per-token records
__global__ __launch_bounds__(256) void router1_kernel(
    const float* __restrict__ x, const float* __restrict__ Wr, const float* __restrict__ br,
    int* __restrict__ erec, float2* __restrict__ wrec, float* __restrict__ partial) {
    __shared__ float ls[NEXP];
    const int tid = threadIdx.x;
    if (tid < NEXP) ls[tid] = 0.0f;
    __syncthreads();

    const int wave = tid >> 6;
    const int lane = tid & 63;
    const int tok0 = blockIdx.x * 16 + wave * 4;

    float acc[4][NEXP];
#pragma unroll
    for (int j = 0; j < 4; ++j)
#pragma unroll
        for (int e = 0; e < NEXP; ++e) acc[j][e] = 0.0f;

#pragma unroll
    for (int it = 0; it < 4; ++it) {
        const float4* w4 = reinterpret_cast<const float4*>(
            Wr + (size_t)(it * 256 + lane * 4) * NEXP);
        float w[24];
#pragma unroll
        for (int q = 0; q < 6; ++q) *reinterpret_cast<float4*>(&w[q * 4]) = w4[q];
#pragma unroll
        for (int j = 0; j < 4; ++j) {
            float4 xv = reinterpret_cast<const float4*>(
                x + (size_t)(tok0 + j) * DDIM)[it * 64 + lane];
            float xa[4] = {xv.x, xv.y, xv.z, xv.w};
#pragma unroll
            for (int i2 = 0; i2 < 4; ++i2)
#pragma unroll
                for (int e = 0; e < NEXP; ++e)
                    acc[j][e] += xa[i2] * w[i2 * NEXP + e];
        }
    }

    float lsacc[NEXP];
#pragma unroll
    for (int e = 0; e < NEXP; ++e) lsacc[e] = 0.0f;

#pragma unroll
    for (int j = 0; j < 4; ++j) {
        float p[NEXP];
        float m = -1e30f;
#pragma unroll
        for (int e = 0; e < NEXP; ++e) {
            float v = acc[j][e];
#pragma unroll
            for (int off = 32; off > 0; off >>= 1) v += __shfl_xor(v, off, 64);
            p[e] = v + br[e];
            m = fmaxf(m, p[e]);
        }
        float s = 0.0f;
#pragma unroll
        for (int e = 0; e < NEXP; ++e) { p[e] = expf(p[e] - m); s += p[e]; }
        const float inv = (1.0f - EPSF) / s;
#pragma unroll
        for (int e = 0; e < NEXP; ++e) p[e] = p[e] * inv + EPSF / (float)NEXP;

        int b1i = 0; float bp = p[0];
#pragma unroll
        for (int e = 1; e < NEXP; ++e) if (p[e] > bp) { bp = p[e]; b1i = e; }
        int b2i = -1; float sp = -1e30f;
#pragma unroll
        for (int e = 0; e < NEXP; ++e) if (e != b1i && p[e] > sp) { sp = p[e]; b2i = e; }

        if (lane == 0) {
            erec[tok0 + j] = b1i | (b2i << 16);
            wrec[tok0 + j] = make_float2(bp, sp);
        }
#pragma unroll
        for (int e = 0; e < NEXP; ++e) lsacc[e] += p[e];
    }

    if (lane == 0) {
#pragma unroll
        for (int e = 0; e < NEXP; ++e) atomicAdd(&ls[e], lsacc[e]);
    }
    __syncthreads();
    if (tid < NEXP) partial[blockIdx.x * NEXP + tid] = ls[tid];
}

// ---------- router phase 2: bucket tokens by unordered expert pair
__global__ __launch_bounds__(1024) void router2_kernel(
    const int* __restrict__ erec, const float2* __restrict__ wrec,
    int* __restrict__ plist, float2* __restrict__ wpair, int* __restrict__ cnt) {
    __shared__ int lc[NPAIR];
    __shared__ int gb[NPAIR];
    const int tid = threadIdx.x;
    if (tid < NPAIR) lc[tid] = 0;
    __syncthreads();

    const int tok = blockIdx.x * 1024 + tid;
    const int er = erec[tok];
    const float2 wr = wrec[tok];
    const int e1 = er & 0xffff;
    const int e2 = er >> 16;
    const int a = min(e1, e2);
    const int b = max(e1, e2);
    const float wa = (a == e1) ? wr.x : wr.y;
    const float wb = (a == e1) ? wr.y : wr.x;
    const int p = a * (11 - a) / 2 + (b - a - 1);

    const int i = atomicAdd(&lc[p], 1);
    __syncthreads();
    if (tid < NPAIR) gb[tid] = atomicAdd(&cnt[tid], lc[tid]);
    __syncthreads();

    const int pos = gb[p] + i;
    plist[p * B_TOK + pos] = tok;
    wpair[p * B_TOK + pos] = make_float2(wa, wb);
}

// ---------- router phase 3 + aux: tile table, and aux scalar (fused, one block)
__global__ void router3_aux_kernel(const int* __restrict__ cnt, int* __restrict__ table,
                                   const float* __restrict__ partial, float* __restrict__ out) {
    const int lane = threadIdx.x;   // 64
    if (lane == 0) {
        int off = 0;
        for (int p = 0; p < NPAIR; ++p) {
            const int t = (cnt[p] + TILE - 1) / TILE;
            for (int i = 0; i < t; ++i) table[1 + off + i] = (p << 16) | i;
            off += t;
        }
        table[0] = off;
    }
    float s[NEXP];
#pragma unroll
    for (int e = 0; e < NEXP; ++e) s[e] = 0.0f;
    for (int i = lane; i < 1024; i += 64) {
#pragma unroll
        for (int e = 0; e < NEXP; ++e) s[e] += partial[i * NEXP + e];
    }
#pragma unroll
    for (int e = 0; e < NEXP; ++e) {
        float v = s[e];
#pragma unroll
        for (int off = 32; off > 0; off >>= 1) v += __shfl_xor(v, off, 64);
        s[e] = v;
    }
    if (lane == 0) {
        float a = 0.0f;
#pragma unroll
        for (int e = 0; e < NEXP; ++e) {
            float ld = s[e] / (float)B_TOK;
            a += ld * logf(ld * (float)NEXP + 1e-9f);
        }
        out[(size_t)B_TOK * DDIM] = a / logf((float)NEXP + 1e-9f);
    }
}

// ---------- pair-fused expert MLP: 32-token tile, 8 waves, whole-x-in-LDS, barrier-free K-loop
__global__ __launch_bounds__(512, 2) void expert_kernel(
    const float* __restrict__ x,
    const unsigned short* __restrict__ w1t,   // (E, H, D) bf16
    const unsigned short* __restrict__ w2t,   // (E, D, H) bf16
    const float* __restrict__ b1,             // (E, H)
    const float* __restrict__ b2,             // (E, D)
    const int* __restrict__ plist, const float2* __restrict__ wpair,
    const int* __restrict__ cnt, const int* __restrict__ table,
    float* __restrict__ out) {
    const int g = blockIdx.x;
    if (g >= table[0]) return;
    const int code = table[1 + g];
    const int p = code >> 16;
    const int lt = code & 0xffff;
    const int n = cnt[p];

    int a, b;
    if      (p < 5)  { a = 0; b = p + 1; }
    else if (p < 9)  { a = 1; b = p - 3; }
    else if (p < 12) { a = 2; b = p - 6; }
    else if (p < 14) { a = 3; b = p - 8; }
    else             { a = 4; b = 5; }

    __shared__ int   tok_l[TILE];
    __shared__ float wa_l[TILE];
    __shared__ float wb_l[TILE];
    // x tile: 32 tok x 1024 k bf16 = 64KB, token-major rows of 2KB, 16B-chunk XOR swizzle.
    // hA [0,16KB) / hB [16KB,32KB) alias the x region after stage-1 completes.
    __shared__ __align__(16) char smem[65536];

    const int tid = threadIdx.x;
    const int lane = tid & 63;
    const int wave = tid >> 6;

    if (tid < TILE) {
        const int gi = lt * TILE + tid;
        if (gi < n) {
            tok_l[tid] = plist[p * B_TOK + gi];
            float2 w2v = wpair[p * B_TOK + gi];
            wa_l[tid] = w2v.x; wb_l[tid] = w2v.y;
        } else { tok_l[tid] = -1; wa_l[tid] = 0.0f; wb_l[tid] = 0.0f; }
    }
    __syncthreads();

    // ---- stage whole x tile into LDS (bf16, swizzled); 16 threads per token
    {
        const int ti = tid >> 4;          // token slot 0..31
        const int q  = tid & 15;
        const int tok_s = tok_l[ti];
        const float* xrow = x + (size_t)(tok_s < 0 ? 0 : tok_s) * DDIM;
#pragma unroll
        for (int it = 0; it < 8; ++it) {
            const int k0 = it * 128 + q * 8;
            float4 f0, f1;
            if (tok_s >= 0) {
                const float4* ps = reinterpret_cast<const float4*>(xrow + k0);
                f0 = ps[0]; f1 = ps[1];
            } else {
                f0 = make_float4(0.f, 0.f, 0.f, 0.f); f1 = f0;
            }
            int4 wv;
            wv.x = pack2bf(f0.x, f0.y); wv.y = pack2bf(f0.z, f0.w);
            wv.z = pack2bf(f1.x, f1.y); wv.w = pack2bf(f1.z, f1.w);
            const int c = k0 >> 3;        // 16B chunk index 0..127
            *reinterpret_cast<int4*>(smem + ti * 2048 + ((c ^ (ti & 7)) << 4)) = wv;
        }
    }
    __syncthreads();

    // ---- stage 1: hX^T(256 x 32) = wX * gelu(W1X^T . x^T + b1X)
    // waves 0-3 -> expert a, waves 4-7 -> expert b; each wave owns 64 h rows.
    const int wexp = (wave < 4) ? a : b;
    const unsigned short* w1e = w1t + (size_t)wexp * HDIM * DDIM;
    const int hrow0 = (wave & 3) * 64;
    const int kofs = (lane >> 4) * 8;

    f32x4 zero4 = {0.f, 0.f, 0.f, 0.f};
    f32x4 acc[4][2];
#pragma unroll
    for (int i = 0; i < 4; ++i) { acc[i][0] = zero4; acc[i][1] = zero4; }

#pragma unroll 4
    for (int kk = 0; kk < DDIM; kk += 32) {
        bf16x8 aF[4], bF[2];
#pragma unroll
        for (int nt = 0; nt < 2; ++nt) {
            const int t = nt * 16 + (lane & 15);
            const int c = (kk >> 3) + (lane >> 4);
            bF[nt] = *reinterpret_cast<const bf16x8*>(
                smem + t * 2048 + ((c ^ (t & 7)) << 4));
        }
#pragma unroll
        for (int mt = 0; mt < 4; ++mt)
            aF[mt] = *reinterpret_cast<const bf16x8*>(
                w1e + (size_t)(hrow0 + mt * 16 + (lane & 15)) * DDIM + kk + kofs);
#pragma unroll
        for (int mt = 0; mt < 4; ++mt)
#pragma unroll
            for (int nt = 0; nt < 2; ++nt)
                acc[mt][nt] = __builtin_amdgcn_mfma_f32_16x16x32_bf16(
                    aF[mt], bF[nt], acc[mt][nt], 0, 0, 0);
    }
    __syncthreads();   // all x reads done; x region may be overwritten

    // gelu + gate-weight scale + write h^T (bf16): hA at 0, hB at 16KB
    char* hdst = smem + ((wave < 4) ? 0 : 16384);
#pragma unroll
    for (int mt = 0; mt < 4; ++mt) {
        const int hh0 = hrow0 + mt * 16 + (lane >> 4) * 4;
        const float4 bb = *reinterpret_cast<const float4*>(b1 + wexp * HDIM + hh0);
#pragma unroll
        for (int nt = 0; nt < 2; ++nt) {
            const int t = nt * 16 + (lane & 15);
            const float wt = (wave < 4) ? wa_l[t] : wb_l[t];
            ushort4 hv;
            hv.x = f2bf(wt * gelu_exact(acc[mt][nt][0] + bb.x));
            hv.y = f2bf(wt * gelu_exact(acc[mt][nt][1] + bb.y));
            hv.z = f2bf(wt * gelu_exact(acc[mt][nt][2] + bb.z));
            hv.w = f2bf(wt * gelu_exact(acc[mt][nt][3] + bb.w));
            int off = t * 512 + hh0 * 2; off ^= (t & 7) << 4;
            *reinterpret_cast<ushort4*>(hdst + off) = hv;
        }
    }
    __syncthreads();

    // ---- stage 2: out(32 x 1024) = hA . W2A + hB . W2B + (wa*b2A + wb*b2B)
    // 8 waves x 128 d-columns each.
    const unsigned short* w2a = w2t + (size_t)a * DDIM * HDIM;
    const unsigned short* w2b = w2t + (size_t)b * DDIM * HDIM;
#pragma unroll 1
    for (int c2 = 0; c2 < 2; ++c2) {
        const int dbase = wave * 128 + c2 * 64;
        f32x4 a2[2][4];
#pragma unroll
        for (int i = 0; i < 2; ++i)
#pragma unroll
            for (int j = 0; j < 4; ++j) a2[i][j] = zero4;

#pragma unroll
        for (int hh0 = 0; hh0 < HDIM; hh0 += 32) {
            bf16x8 aF[2], bF[4];
#pragma unroll
            for (int mt = 0; mt < 2; ++mt) {
                const int t = mt * 16 + (lane & 15);
                int off = t * 512 + (hh0 + kofs) * 2; off ^= (t & 7) << 4;
                aF[mt] = *reinterpret_cast<const bf16x8*>(smem + off);
            }
#pragma unroll
            for (int nt = 0; nt < 4; ++nt)
                bF[nt] = *reinterpret_cast<const bf16x8*>(
                    w2a + (size_t)(dbase + nt * 16 + (lane & 15)) * HDIM + hh0 + kofs);
#pragma unroll
            for (int mt = 0; mt < 2; ++mt)
#pragma unroll
                for (int nt = 0; nt < 4; ++nt)
                    a2[mt][nt] = __builtin_amdgcn_mfma_f32_16x16x32_bf16(
                        aF[mt], bF[nt], a2[mt][nt], 0, 0, 0);
        }
#pragma unroll
        for (int hh0 = 0; hh0 < HDIM; hh0 += 32) {
            bf16x8 aF[2], bF[4];
#pragma unroll
            for (int mt = 0; mt < 2; ++mt) {
                const int t = mt * 16 + (lane & 15);
                int off = t * 512 + (hh0 + kofs) * 2; off ^= (t & 7) << 4;
                aF[mt] = *reinterpret_cast<const bf16x8*>(smem + 16384 + off);
            }
#pragma unroll
            for (int nt = 0; nt < 4; ++nt)
                bF[nt] = *reinterpret_cast<const bf16x8*>(
                    w2b + (size_t)(dbase + nt * 16 + (lane & 15)) * HDIM + hh0 + kofs);
#pragma unroll
            for (int mt = 0; mt < 2; ++mt)
#pragma unroll
                for (int nt = 0; nt < 4; ++nt)
                    a2[mt][nt] = __builtin_amdgcn_mfma_f32_16x16x32_bf16(
                        aF[mt], bF[nt], a2[mt][nt], 0, 0, 0);
        }

        // epilogue: single plain store per output element
#pragma unroll
        for (int mt = 0; mt < 2; ++mt) {
            const int t0 = mt * 16 + (lane >> 4) * 4;
            int tkj[4]; float waj[4], wbj[4];
#pragma unroll
            for (int j = 0; j < 4; ++j) {
                tkj[j] = tok_l[t0 + j]; waj[j] = wa_l[t0 + j]; wbj[j] = wb_l[t0 + j];
            }
#pragma unroll
            for (int nt = 0; nt < 4; ++nt) {
                const int d = dbase + nt * 16 + (lane & 15);
                const float bA = b2[a * DDIM + d];
                const float bB = b2[b * DDIM + d];
#pragma unroll
                for (int j = 0; j < 4; ++j) {
                    if (tkj[j] >= 0)
                        out[(size_t)tkj[j] * DDIM + d] =
                            a2[mt][nt][j] + waj[j] * bA + wbj[j] * bB;
                }
            }
        }
    }
}

extern "C" void kernel_launch(void* const* d_in, const int* in_sizes, int n_in,
                              void* d_out, int out_size, void* d_ws, size_t ws_size,
                              hipStream_t stream) {
    const float* x  = (const float*)d_in[0];
    const float* Wr = (const float*)d_in[1];
    const float* br = (const float*)d_in[2];
    const float* W1 = (const float*)d_in[3];
    const float* b1 = (const float*)d_in[4];
    const float* W2 = (const float*)d_in[5];
    const float* b2 = (const float*)d_in[6];
    float* out = (float*)d_out;

    char* ws = (char*)d_ws;
    unsigned short* w1t   = (unsigned short*)(ws + 0);          // 3,145,728
    unsigned short* w2t   = (unsigned short*)(ws + 3145728);    // 3,145,728
    int*            plist = (int*)(ws + 6291456);               //   983,040
    float2*         wpair = (float2*)(ws + 7274496);            // 1,966,080
    int*            erec  = (int*)(ws + 9240576);               //    65,536
    float2*         wrec  = (float2*)(ws + 9306112);            //   131,072
    float*          partial = (float*)(ws + 9437184);           //    24,576
    int*            cnt   = (int*)(ws + 9461760);               //       256
    int*            table = (int*)(ws + 9462016);               //     2,560

    hipMemsetAsync(cnt, 0, 256, stream);

    transpose_convert_kernel<<<dim3(HDIM / 32, DDIM / 32, NEXP), dim3(32, 8), 0, stream>>>(
        W1, w1t, DDIM, HDIM);
    transpose_convert_kernel<<<dim3(DDIM / 32, HDIM / 32, NEXP), dim3(32, 8), 0, stream>>>(
        W2, w2t, HDIM, DDIM);

    router1_kernel<<<dim3(B_TOK / 16), dim3(256), 0, stream>>>(x, Wr, br, erec, wrec, partial);
    router2_kernel<<<dim3(B_TOK / 1024), dim3(1024), 0, stream>>>(erec, wrec, plist, wpair, cnt);
    router3_aux_kernel<<<1, 64, 0, stream>>>(cnt, table, partial, out);
    expert_kernel<<<dim3(MAXTILES), dim3(512), 0, stream>>>(
        x, w1t, w2t, b1, b2, plist, wpair, cnt, table, out);
}

// Round 9
// 302.307 us; speedup vs baseline: 1.4517x; 1.2793x over previous
//
#include <hip/hip_runtime.h>
#include <hip/hip_bf16.h>
#include <math.h>

#define B_TOK 16384
#define DDIM  1024
#define NEXP  6
#define NPAIR 15
#define HDIM  256
#define EPSF  0.1f
#define TILE  32
#define MAXTILES (B_TOK / TILE + NPAIR)   // 527

typedef float f32x4 __attribute__((ext_vector_type(4)));
typedef short bf16x8 __attribute__((ext_vector_type(8)));

__device__ __forceinline__ unsigned short f2bf(float f) {
    unsigned int u = __float_as_uint(f);
    u += 0x7FFFu + ((u >> 16) & 1u);
    return (unsigned short)(u >> 16);
}
__device__ __forceinline__ int pack2bf(float a, float b) {
    return (int)f2bf(a) | ((int)f2bf(b) << 16);
}
__device__ __forceinline__ float gelu_exact(float v) {
    return 0.5f * v * (1.0f + erff(v * 0.70710678118654752440f));
}

// ---------- pack W1 (E, D=1024, H=256) f32 -> w1p fragment-blob layout bf16
// blob(e, mg in [0,16), ks in [0,32)): 64 lanes x 8 bf16, lane l holds
// W1[e][d0+j][h], d0 = ks*32 + (l>>4)*8, h = mg*16 + (l&15).  1KB/blob contiguous.
__global__ __launch_bounds__(256) void pack_w1_kernel(
    const float* __restrict__ W1, unsigned short* __restrict__ w1p) {
    const int lane = threadIdx.x & 63;
    const int blob = blockIdx.x * 4 + (threadIdx.x >> 6);
    const int e  = blob >> 9;          // /512
    const int rm = blob & 511;
    const int mg = rm >> 5;
    const int ks = rm & 31;
    const int d0 = ks * 32 + (lane >> 4) * 8;
    const int h  = mg * 16 + (lane & 15);
    const float* src = W1 + ((size_t)e * DDIM + d0) * HDIM + h;
    ushort4 o0, o1;
    o0.x = f2bf(src[0 * HDIM]); o0.y = f2bf(src[1 * HDIM]);
    o0.z = f2bf(src[2 * HDIM]); o0.w = f2bf(src[3 * HDIM]);
    o1.x = f2bf(src[4 * HDIM]); o1.y = f2bf(src[5 * HDIM]);
    o1.z = f2bf(src[6 * HDIM]); o1.w = f2bf(src[7 * HDIM]);
    unsigned short* dst = w1p + ((size_t)blob * 512) + lane * 8;
    *reinterpret_cast<ushort4*>(dst)     = o0;
    *reinterpret_cast<ushort4*>(dst + 4) = o1;
}

// ---------- pack W2 (E, H=256, D=1024) f32 -> w2p fragment-blob layout bf16
// blob(e, dg in [0,64), hs in [0,8)): lane l holds W2[e][h0+j][d],
// h0 = hs*32 + (l>>4)*8, d = dg*16 + (l&15).
__global__ __launch_bounds__(256) void pack_w2_kernel(
    const float* __restrict__ W2, unsigned short* __restrict__ w2p) {
    const int lane = threadIdx.x & 63;
    const int blob = blockIdx.x * 4 + (threadIdx.x >> 6);
    const int e  = blob >> 9;          // /512
    const int rm = blob & 511;
    const int dg = rm >> 3;
    const int hs = rm & 7;
    const int h0 = hs * 32 + (lane >> 4) * 8;
    const int d  = dg * 16 + (lane & 15);
    const float* src = W2 + ((size_t)e * HDIM + h0) * DDIM + d;
    ushort4 o0, o1;
    o0.x = f2bf(src[0 * DDIM]); o0.y = f2bf(src[1 * DDIM]);
    o0.z = f2bf(src[2 * DDIM]); o0.w = f2bf(src[3 * DDIM]);
    o1.x = f2bf(src[4 * DDIM]); o1.y = f2bf(src[5 * DDIM]);
    o1.z = f2bf(src[6 * DDIM]); o1.w = f2bf(src[7 * DDIM]);
    unsigned short* dst = w2p + ((size_t)blob * 512) + lane * 8;
    *reinterpret_cast<ushort4*>(dst)     = o0;
    *reinterpret_cast<ushort4*>(dst + 4) = o1;
}

// ---------- router phase 1: logits, softmax, eps-mix, top-2 -> per-token records
__global__ __launch_bounds__(256) void router1_kernel(
    const float* __restrict__ x, const float* __restrict__ Wr, const float* __restrict__ br,
    int* __restrict__ erec, float2* __restrict__ wrec, float* __restrict__ partial) {
    __shared__ float ls[NEXP];
    const int tid = threadIdx.x;
    if (tid < NEXP) ls[tid] = 0.0f;
    __syncthreads();

    const int wave = tid >> 6;
    const int lane = tid & 63;
    const int tok0 = blockIdx.x * 16 + wave * 4;

    float acc[4][NEXP];
#pragma unroll
    for (int j = 0; j < 4; ++j)
#pragma unroll
        for (int e = 0; e < NEXP; ++e) acc[j][e] = 0.0f;

#pragma unroll
    for (int it = 0; it < 4; ++it) {
        const float4* w4 = reinterpret_cast<const float4*>(
            Wr + (size_t)(it * 256 + lane * 4) * NEXP);
        float w[24];
#pragma unroll
        for (int q = 0; q < 6; ++q) *reinterpret_cast<float4*>(&w[q * 4]) = w4[q];
#pragma unroll
        for (int j = 0; j < 4; ++j) {
            float4 xv = reinterpret_cast<const float4*>(
                x + (size_t)(tok0 + j) * DDIM)[it * 64 + lane];
            float xa[4] = {xv.x, xv.y, xv.z, xv.w};
#pragma unroll
            for (int i2 = 0; i2 < 4; ++i2)
#pragma unroll
                for (int e = 0; e < NEXP; ++e)
                    acc[j][e] += xa[i2] * w[i2 * NEXP + e];
        }
    }

    float lsacc[NEXP];
#pragma unroll
    for (int e = 0; e < NEXP; ++e) lsacc[e] = 0.0f;

#pragma unroll
    for (int j = 0; j < 4; ++j) {
        float p[NEXP];
        float m = -1e30f;
#pragma unroll
        for (int e = 0; e < NEXP; ++e) {
            float v = acc[j][e];
#pragma unroll
            for (int off = 32; off > 0; off >>= 1) v += __shfl_xor(v, off, 64);
            p[e] = v + br[e];
            m = fmaxf(m, p[e]);
        }
        float s = 0.0f;
#pragma unroll
        for (int e = 0; e < NEXP; ++e) { p[e] = expf(p[e] - m); s += p[e]; }
        const float inv = (1.0f - EPSF) / s;
#pragma unroll
        for (int e = 0; e < NEXP; ++e) p[e] = p[e] * inv + EPSF / (float)NEXP;

        int b1i = 0; float bp = p[0];
#pragma unroll
        for (int e = 1; e < NEXP; ++e) if (p[e] > bp) { bp = p[e]; b1i = e; }
        int b2i = -1; float sp = -1e30f;
#pragma unroll
        for (int e = 0; e < NEXP; ++e) if (e != b1i && p[e] > sp) { sp = p[e]; b2i = e; }

        if (lane == 0) {
            erec[tok0 + j] = b1i | (b2i << 16);
            wrec[tok0 + j] = make_float2(bp, sp);
        }
#pragma unroll
        for (int e = 0; e < NEXP; ++e) lsacc[e] += p[e];
    }

    if (lane == 0) {
#pragma unroll
        for (int e = 0; e < NEXP; ++e) atomicAdd(&ls[e], lsacc[e]);
    }
    __syncthreads();
    if (tid < NEXP) partial[blockIdx.x * NEXP + tid] = ls[tid];
}

// ---------- router phase 2: bucket tokens by unordered expert pair
__global__ __launch_bounds__(1024) void router2_kernel(
    const int* __restrict__ erec, const float2* __restrict__ wrec,
    int* __restrict__ plist, float2* __restrict__ wpair, int* __restrict__ cnt) {
    __shared__ int lc[NPAIR];
    __shared__ int gb[NPAIR];
    const int tid = threadIdx.x;
    if (tid < NPAIR) lc[tid] = 0;
    __syncthreads();

    const int tok = blockIdx.x * 1024 + tid;
    const int er = erec[tok];
    const float2 wr = wrec[tok];
    const int e1 = er & 0xffff;
    const int e2 = er >> 16;
    const int a = min(e1, e2);
    const int b = max(e1, e2);
    const float wa = (a == e1) ? wr.x : wr.y;
    const float wb = (a == e1) ? wr.y : wr.x;
    const int p = a * (11 - a) / 2 + (b - a - 1);

    const int i = atomicAdd(&lc[p], 1);
    __syncthreads();
    if (tid < NPAIR) gb[tid] = atomicAdd(&cnt[tid], lc[tid]);
    __syncthreads();

    const int pos = gb[p] + i;
    plist[p * B_TOK + pos] = tok;
    wpair[p * B_TOK + pos] = make_float2(wa, wb);
}

// ---------- router phase 3 + aux: tile table, and aux scalar (fused, one block)
__global__ void router3_aux_kernel(const int* __restrict__ cnt, int* __restrict__ table,
                                   const float* __restrict__ partial, float* __restrict__ out) {
    const int lane = threadIdx.x;   // 64
    if (lane == 0) {
        int off = 0;
        for (int p = 0; p < NPAIR; ++p) {
            const int t = (cnt[p] + TILE - 1) / TILE;
            for (int i = 0; i < t; ++i) table[1 + off + i] = (p << 16) | i;
            off += t;
        }
        table[0] = off;
    }
    float s[NEXP];
#pragma unroll
    for (int e = 0; e < NEXP; ++e) s[e] = 0.0f;
    for (int i = lane; i < 1024; i += 64) {
#pragma unroll
        for (int e = 0; e < NEXP; ++e) s[e] += partial[i * NEXP + e];
    }
#pragma unroll
    for (int e = 0; e < NEXP; ++e) {
        float v = s[e];
#pragma unroll
        for (int off = 32; off > 0; off >>= 1) v += __shfl_xor(v, off, 64);
        s[e] = v;
    }
    if (lane == 0) {
        float a = 0.0f;
#pragma unroll
        for (int e = 0; e < NEXP; ++e) {
            float ld = s[e] / (float)B_TOK;
            a += ld * logf(ld * (float)NEXP + 1e-9f);
        }
        out[(size_t)B_TOK * DDIM] = a / logf((float)NEXP + 1e-9f);
    }
}

// ---------- pair-fused expert MLP: 32-token tile, 8 waves, whole-x-in-LDS,
// barrier-free K-loop, fragment-packed weight loads (1KB coalesced per fragment).
__global__ __launch_bounds__(512, 2) void expert_kernel(
    const float* __restrict__ x,
    const unsigned short* __restrict__ w1p,   // packed: (E,16,32) blobs of 1KB
    const unsigned short* __restrict__ w2p,   // packed: (E,64,8)  blobs of 1KB
    const float* __restrict__ b1,             // (E, H)
    const float* __restrict__ b2,             // (E, D)
    const int* __restrict__ plist, const float2* __restrict__ wpair,
    const int* __restrict__ cnt, const int* __restrict__ table,
    float* __restrict__ out) {
    const int g = blockIdx.x;
    if (g >= table[0]) return;
    const int code = table[1 + g];
    const int p = code >> 16;
    const int lt = code & 0xffff;
    const int n = cnt[p];

    int a, b;
    if      (p < 5)  { a = 0; b = p + 1; }
    else if (p < 9)  { a = 1; b = p - 3; }
    else if (p < 12) { a = 2; b = p - 6; }
    else if (p < 14) { a = 3; b = p - 8; }
    else             { a = 4; b = 5; }

    __shared__ int   tok_l[TILE];
    __shared__ float wa_l[TILE];
    __shared__ float wb_l[TILE];
    // x tile: 32 tok x 1024 k bf16 = 64KB, token-major rows of 2KB, 16B-chunk XOR swizzle.
    // hA [0,16KB) / hB [16KB,32KB) alias the x region after stage-1 completes.
    __shared__ __align__(16) char smem[65536];

    const int tid = threadIdx.x;
    const int lane = tid & 63;
    const int wave = tid >> 6;

    if (tid < TILE) {
        const int gi = lt * TILE + tid;
        if (gi < n) {
            tok_l[tid] = plist[p * B_TOK + gi];
            float2 w2v = wpair[p * B_TOK + gi];
            wa_l[tid] = w2v.x; wb_l[tid] = w2v.y;
        } else { tok_l[tid] = -1; wa_l[tid] = 0.0f; wb_l[tid] = 0.0f; }
    }
    __syncthreads();

    // ---- stage whole x tile into LDS (bf16, swizzled); 16 threads per token
    {
        const int ti = tid >> 4;          // token slot 0..31
        const int q  = tid & 15;
        const int tok_s = tok_l[ti];
        const float* xrow = x + (size_t)(tok_s < 0 ? 0 : tok_s) * DDIM;
#pragma unroll
        for (int it = 0; it < 8; ++it) {
            const int k0 = it * 128 + q * 8;
            float4 f0, f1;
            if (tok_s >= 0) {
                const float4* ps = reinterpret_cast<const float4*>(xrow + k0);
                f0 = ps[0]; f1 = ps[1];
            } else {
                f0 = make_float4(0.f, 0.f, 0.f, 0.f); f1 = f0;
            }
            int4 wv;
            wv.x = pack2bf(f0.x, f0.y); wv.y = pack2bf(f0.z, f0.w);
            wv.z = pack2bf(f1.x, f1.y); wv.w = pack2bf(f1.z, f1.w);
            const int c = k0 >> 3;        // 16B chunk index 0..127
            *reinterpret_cast<int4*>(smem + ti * 2048 + ((c ^ (ti & 7)) << 4)) = wv;
        }
    }
    __syncthreads();

    // ---- stage 1: hX^T(256 x 32) = wX * gelu(W1X^T . x^T + b1X)
    // waves 0-3 -> expert a, waves 4-7 -> expert b; each wave owns 64 h rows.
    const int wexp = (wave < 4) ? a : b;
    const int hrow0 = (wave & 3) * 64;
    const int kofs = (lane >> 4) * 8;

    // packed W1 base for this wave's 4 fragment-row-groups: mg = (wave&3)*4 + mt
    const unsigned short* w1base = w1p + ((size_t)wexp * 16 + (wave & 3) * 4) * 32 * 512
                                       + lane * 8;

    f32x4 zero4 = {0.f, 0.f, 0.f, 0.f};
    f32x4 acc[4][2];
#pragma unroll
    for (int i = 0; i < 4; ++i) { acc[i][0] = zero4; acc[i][1] = zero4; }

#pragma unroll 4
    for (int ks = 0; ks < 32; ++ks) {
        const int kk = ks * 32;
        bf16x8 aF[4], bF[2];
#pragma unroll
        for (int nt = 0; nt < 2; ++nt) {
            const int t = nt * 16 + (lane & 15);
            const int c = (kk >> 3) + (lane >> 4);
            bF[nt] = *reinterpret_cast<const bf16x8*>(
                smem + t * 2048 + ((c ^ (t & 7)) << 4));
        }
#pragma unroll
        for (int mt = 0; mt < 4; ++mt)
            aF[mt] = *reinterpret_cast<const bf16x8*>(
                w1base + ((size_t)mt * 32 + ks) * 512);
#pragma unroll
        for (int mt = 0; mt < 4; ++mt)
#pragma unroll
            for (int nt = 0; nt < 2; ++nt)
                acc[mt][nt] = __builtin_amdgcn_mfma_f32_16x16x32_bf16(
                    aF[mt], bF[nt], acc[mt][nt], 0, 0, 0);
    }
    __syncthreads();   // all x reads done; x region may be overwritten

    // gelu + gate-weight scale + write h^T (bf16): hA at 0, hB at 16KB
    char* hdst = smem + ((wave < 4) ? 0 : 16384);
#pragma unroll
    for (int mt = 0; mt < 4; ++mt) {
        const int hh0 = hrow0 + mt * 16 + (lane >> 4) * 4;
        const float4 bb = *reinterpret_cast<const float4*>(b1 + wexp * HDIM + hh0);
#pragma unroll
        for (int nt = 0; nt < 2; ++nt) {
            const int t = nt * 16 + (lane & 15);
            const float wt = (wave < 4) ? wa_l[t] : wb_l[t];
            ushort4 hv;
            hv.x = f2bf(wt * gelu_exact(acc[mt][nt][0] + bb.x));
            hv.y = f2bf(wt * gelu_exact(acc[mt][nt][1] + bb.y));
            hv.z = f2bf(wt * gelu_exact(acc[mt][nt][2] + bb.z));
            hv.w = f2bf(wt * gelu_exact(acc[mt][nt][3] + bb.w));
            int off = t * 512 + hh0 * 2; off ^= (t & 7) << 4;
            *reinterpret_cast<ushort4*>(hdst + off) = hv;
        }
    }
    __syncthreads();

    // ---- stage 2: out(32 x 1024) = hA . W2A + hB . W2B + (wa*b2A + wb*b2B)
    // 8 waves x 128 d-columns each.  Packed W2: dg = wave*8 + c2*4 + nt.
#pragma unroll 1
    for (int c2 = 0; c2 < 2; ++c2) {
        const int dbase = wave * 128 + c2 * 64;
        const unsigned short* w2abase = w2p + ((size_t)a * 64 + wave * 8 + c2 * 4) * 8 * 512
                                            + lane * 8;
        const unsigned short* w2bbase = w2p + ((size_t)b * 64 + wave * 8 + c2 * 4) * 8 * 512
                                            + lane * 8;
        f32x4 a2[2][4];
#pragma unroll
        for (int i = 0; i < 2; ++i)
#pragma unroll
            for (int j = 0; j < 4; ++j) a2[i][j] = zero4;

#pragma unroll
        for (int hs = 0; hs < 8; ++hs) {
            const int hh0 = hs * 32;
            bf16x8 aF[2], bF[4];
#pragma unroll
            for (int mt = 0; mt < 2; ++mt) {
                const int t = mt * 16 + (lane & 15);
                int off = t * 512 + (hh0 + kofs) * 2; off ^= (t & 7) << 4;
                aF[mt] = *reinterpret_cast<const bf16x8*>(smem + off);
            }
#pragma unroll
            for (int nt = 0; nt < 4; ++nt)
                bF[nt] = *reinterpret_cast<const bf16x8*>(
                    w2abase + ((size_t)nt * 8 + hs) * 512);
#pragma unroll
            for (int mt = 0; mt < 2; ++mt)
#pragma unroll
                for (int nt = 0; nt < 4; ++nt)
                    a2[mt][nt] = __builtin_amdgcn_mfma_f32_16x16x32_bf16(
                        aF[mt], bF[nt], a2[mt][nt], 0, 0, 0);
        }
#pragma unroll
        for (int hs = 0; hs < 8; ++hs) {
            const int hh0 = hs * 32;
            bf16x8 aF[2], bF[4];
#pragma unroll
            for (int mt = 0; mt < 2; ++mt) {
                const int t = mt * 16 + (lane & 15);
                int off = t * 512 + (hh0 + kofs) * 2; off ^= (t & 7) << 4;
                aF[mt] = *reinterpret_cast<const bf16x8*>(smem + 16384 + off);
            }
#pragma unroll
            for (int nt = 0; nt < 4; ++nt)
                bF[nt] = *reinterpret_cast<const bf16x8*>(
                    w2bbase + ((size_t)nt * 8 + hs) * 512);
#pragma unroll
            for (int mt = 0; mt < 2; ++mt)
#pragma unroll
                for (int nt = 0; nt < 4; ++nt)
                    a2[mt][nt] = __builtin_amdgcn_mfma_f32_16x16x32_bf16(
                        aF[mt], bF[nt], a2[mt][nt], 0, 0, 0);
        }

        // epilogue: single plain store per output element
#pragma unroll
        for (int mt = 0; mt < 2; ++mt) {
            const int t0 = mt * 16 + (lane >> 4) * 4;
            int tkj[4]; float waj[4], wbj[4];
#pragma unroll
            for (int j = 0; j < 4; ++j) {
                tkj[j] = tok_l[t0 + j]; waj[j] = wa_l[t0 + j]; wbj[j] = wb_l[t0 + j];
            }
#pragma unroll
            for (int nt = 0; nt < 4; ++nt) {
                const int d = dbase + nt * 16 + (lane & 15);
                const float bA = b2[a * DDIM + d];
                const float bB = b2[b * DDIM + d];
#pragma unroll
                for (int j = 0; j < 4; ++j) {
                    if (tkj[j] >= 0)
                        out[(size_t)tkj[j] * DDIM + d] =
                            a2[mt][nt][j] + waj[j] * bA + wbj[j] * bB;
                }
            }
        }
    }
}

extern "C" void kernel_launch(void* const* d_in, const int* in_sizes, int n_in,
                              void* d_out, int out_size, void* d_ws, size_t ws_size,
                              hipStream_t stream) {
    const float* x  = (const float*)d_in[0];
    const float* Wr = (const float*)d_in[1];
    const float* br = (const float*)d_in[2];
    const float* W1 = (const float*)d_in[3];
    const float* b1 = (const float*)d_in[4];
    const float* W2 = (const float*)d_in[5];
    const float* b2 = (const float*)d_in[6];
    float* out = (float*)d_out;

    char* ws = (char*)d_ws;
    unsigned short* w1p   = (unsigned short*)(ws + 0);          // 3,145,728
    unsigned short* w2p   = (unsigned short*)(ws + 3145728);    // 3,145,728
    int*            plist = (int*)(ws + 6291456);               //   983,040
    float2*         wpair = (float2*)(ws + 7274496);            // 1,966,080
    int*            erec  = (int*)(ws + 9240576);               //    65,536
    float2*         wrec  = (float2*)(ws + 9306112);            //   131,072
    float*          partial = (float*)(ws + 9437184);           //    24,576
    int*            cnt   = (int*)(ws + 9461760);               //       256
    int*            table = (int*)(ws + 9462016);               //     2,560

    hipMemsetAsync(cnt, 0, 256, stream);

    // 3072 blobs each; 4 blobs per 256-thread block
    pack_w1_kernel<<<dim3(768), dim3(256), 0, stream>>>(W1, w1p);
    pack_w2_kernel<<<dim3(768), dim3(256), 0, stream>>>(W2, w2p);

    router1_kernel<<<dim3(B_TOK / 16), dim3(256), 0, stream>>>(x, Wr, br, erec, wrec, partial);
    router2_kernel<<<dim3(B_TOK / 1024), dim3(1024), 0, stream>>>(erec, wrec, plist, wpair, cnt);
    router3_aux_kernel<<<1, 64, 0, stream>>>(cnt, table, partial, out);
    expert_kernel<<<dim3(MAXTILES), dim3(512), 0, stream>>>(
        x, w1p, w2p, b1, b2, plist, wpair, cnt, table, out);
}